// Round 1
// baseline (911.014 us; speedup 1.0000x reference)
//
#include <hip/hip_runtime.h>

// SocialPoolingLayer: fused edge-MLP (relu(pair@W1+b1)@W2+b2, sigmoid gate, elemwise
// product) + scatter-mean by src node.
// Round 1: fp32 register-tiled GEMMs, weights from global (L1-resident), pair tile in
// LDS, unsafeAtomicAdd scatter. Structured so GEMMs can be swapped to bf16 MFMA later.

constexpr int D      = 64;
constexpr int TWO_D  = 128;
constexpr int TILE   = 64;    // edges per block
constexpr int BLOCK  = 256;
constexpr int HPAD   = D + 4; // 68 floats: row stride 272B = 16B-aligned, banks spread

__global__ __launch_bounds__(BLOCK, 2)
void edge_mlp_scatter(const float* __restrict__ node_emb,
                      const int*   __restrict__ edge_index,   // [2][E] flat, row0=src row1=dst
                      const float* __restrict__ W1, const float* __restrict__ b1,
                      const float* __restrict__ W2, const float* __restrict__ b2,
                      const float* __restrict__ Wg, const float* __restrict__ bg,
                      float* __restrict__ summed,              // [N][D] pre-zeroed
                      float* __restrict__ counts,              // [N]    pre-zeroed
                      int E)
{
    __shared__ float pairT[TWO_D][TILE];  // [k][e]  32 KB
    __shared__ float hS[TILE][HPAD];      // [e][k]  17 KB (reused for h then interaction)
    __shared__ int   srcIds[TILE];

    const int tid = threadIdx.x;

    // ---- stage pair embeddings (gather), transposed into LDS ----
    {
        const int e  = tid >> 2;        // 0..63
        const int q  = tid & 3;         // quarter of the 64-float row
        const int eg = blockIdx.x * TILE + e;
        if (eg < E) {
            const int s  = edge_index[eg];
            const int dn = edge_index[E + eg];
            if (q == 0) srcIds[e] = s;
            const float4* srow = (const float4*)(node_emb + (size_t)s  * D) + q * 4;
            const float4* drow = (const float4*)(node_emb + (size_t)dn * D) + q * 4;
#pragma unroll
            for (int r = 0; r < 4; ++r) {
                const float4 f = srow[r];
                const float4 g = drow[r];
                const int k0 = q * 16 + r * 4;
                pairT[k0 + 0][e] = f.x; pairT[k0 + 1][e] = f.y;
                pairT[k0 + 2][e] = f.z; pairT[k0 + 3][e] = f.w;
                pairT[64 + k0 + 0][e] = g.x; pairT[64 + k0 + 1][e] = g.y;
                pairT[64 + k0 + 2][e] = g.z; pairT[64 + k0 + 3][e] = g.w;
            }
        } else {
            if (q == 0) srcIds[e] = -1;
#pragma unroll
            for (int r = 0; r < 4; ++r) {
                const int k0 = q * 16 + r * 4;
#pragma unroll
                for (int c = 0; c < 4; ++c) { pairT[k0 + c][e] = 0.f; pairT[64 + k0 + c][e] = 0.f; }
            }
        }
    }
    __syncthreads();

    // one count atomic per valid edge
    if (tid < TILE) {
        const int s = srcIds[tid];
        if (s >= 0) unsafeAtomicAdd(&counts[s], 1.0f);
    }

    const int ty = tid >> 4;      // edge group 0..15  -> edges 4ty..4ty+3
    const int tx = tid & 15;      // out  group 0..15  -> cols  4tx..4tx+3
    const int r0 = 4 * ty, c0 = 4 * tx;

    // ---- GEMM1: h = relu(pair @ W1 + b1)   A: LDS pairT, B: global W1 (L1) ----
    float acc[4][4] = {};
#pragma unroll 4
    for (int k = 0; k < TWO_D; ++k) {
        const float4 a = *(const float4*)&pairT[k][r0];
        const float4 b = *(const float4*)&W1[k * D + c0];
        const float av[4] = {a.x, a.y, a.z, a.w};
        const float bv[4] = {b.x, b.y, b.z, b.w};
#pragma unroll
        for (int i = 0; i < 4; ++i)
#pragma unroll
            for (int j = 0; j < 4; ++j) acc[i][j] += av[i] * bv[j];
    }
    {
        const float4 bb = *(const float4*)&b1[c0];
        const float bv[4] = {bb.x, bb.y, bb.z, bb.w};
#pragma unroll
        for (int i = 0; i < 4; ++i) {
            float4 h;
            h.x = fmaxf(acc[i][0] + bv[0], 0.f);
            h.y = fmaxf(acc[i][1] + bv[1], 0.f);
            h.z = fmaxf(acc[i][2] + bv[2], 0.f);
            h.w = fmaxf(acc[i][3] + bv[3], 0.f);
            *(float4*)&hS[r0 + i][c0] = h;
        }
    }
    __syncthreads();

    // ---- GEMM2: interaction = h @ W2 + b2 ----
    float acc2[4][4] = {};
#pragma unroll 2
    for (int k4 = 0; k4 < D; k4 += 4) {
        float4 ar[4];
#pragma unroll
        for (int i = 0; i < 4; ++i) ar[i] = *(const float4*)&hS[r0 + i][k4];
#pragma unroll
        for (int kk = 0; kk < 4; ++kk) {
            const float4 b = *(const float4*)&W2[(k4 + kk) * D + c0];
            const float bv[4] = {b.x, b.y, b.z, b.w};
#pragma unroll
            for (int i = 0; i < 4; ++i) {
                const float a = (&ar[i].x)[kk];
#pragma unroll
                for (int j = 0; j < 4; ++j) acc2[i][j] += a * bv[j];
            }
        }
    }
    {
        const float4 bb = *(const float4*)&b2[c0];
#pragma unroll
        for (int i = 0; i < 4; ++i) {
            acc2[i][0] += bb.x; acc2[i][1] += bb.y; acc2[i][2] += bb.z; acc2[i][3] += bb.w;
        }
    }
    __syncthreads();   // all GEMM2 reads of hS done before overwrite
#pragma unroll
    for (int i = 0; i < 4; ++i) {
        float4 v;
        v.x = acc2[i][0]; v.y = acc2[i][1]; v.z = acc2[i][2]; v.w = acc2[i][3];
        *(float4*)&hS[r0 + i][c0] = v;
    }
    __syncthreads();

    // ---- GEMM3: gate_pre = interaction @ Wg + bg ----
    float accg[4][4] = {};
#pragma unroll 2
    for (int k4 = 0; k4 < D; k4 += 4) {
        float4 ar[4];
#pragma unroll
        for (int i = 0; i < 4; ++i) ar[i] = *(const float4*)&hS[r0 + i][k4];
#pragma unroll
        for (int kk = 0; kk < 4; ++kk) {
            const float4 b = *(const float4*)&Wg[(k4 + kk) * D + c0];
            const float bv[4] = {b.x, b.y, b.z, b.w};
#pragma unroll
            for (int i = 0; i < 4; ++i) {
                const float a = (&ar[i].x)[kk];
#pragma unroll
                for (int j = 0; j < 4; ++j) accg[i][j] += a * bv[j];
            }
        }
    }

    // ---- sigmoid gate, gated = interaction * gate, scatter-add to summed[src] ----
    {
        const float4 bb = *(const float4*)&bg[c0];
        const float bgv[4] = {bb.x, bb.y, bb.z, bb.w};
#pragma unroll
        for (int i = 0; i < 4; ++i) {
            const int s = srcIds[r0 + i];
            if (s < 0) continue;
            float* dp = summed + (size_t)s * D + c0;
#pragma unroll
            for (int j = 0; j < 4; ++j) {
                const float g = 1.0f / (1.0f + __expf(-(accg[i][j] + bgv[j])));
                unsafeAtomicAdd(&dp[j], acc2[i][j] * g);
            }
        }
    }
}

__global__ void finalize_mean(float* __restrict__ out,
                              const float* __restrict__ counts,
                              int total)
{
    const int i = blockIdx.x * blockDim.x + threadIdx.x;
    if (i < total) {
        out[i] = out[i] / fmaxf(counts[i >> 6], 1.0f);
    }
}

extern "C" void kernel_launch(void* const* d_in, const int* in_sizes, int n_in,
                              void* d_out, int out_size, void* d_ws, size_t ws_size,
                              hipStream_t stream) {
    const float* node_emb   = (const float*)d_in[0];
    const int*   edge_index = (const int*)d_in[1];
    const float* W1 = (const float*)d_in[2];
    const float* b1 = (const float*)d_in[3];
    const float* W2 = (const float*)d_in[4];
    const float* b2 = (const float*)d_in[5];
    const float* Wg = (const float*)d_in[6];
    const float* bg = (const float*)d_in[7];

    const int N = in_sizes[0] / D;
    const int E = in_sizes[1] / 2;

    float* summed = (float*)d_out;       // accumulate in-place in d_out
    float* counts = (float*)d_ws;        // N floats of scratch

    hipMemsetAsync(summed, 0, sizeof(float) * (size_t)N * D, stream);
    hipMemsetAsync(counts, 0, sizeof(float) * (size_t)N, stream);

    const int ntiles = (E + TILE - 1) / TILE;
    edge_mlp_scatter<<<ntiles, BLOCK, 0, stream>>>(node_emb, edge_index,
                                                   W1, b1, W2, b2, Wg, bg,
                                                   summed, counts, E);

    const int total = N * D;
    finalize_mean<<<(total + 255) / 256, 256, 0, stream>>>(summed, counts, total);
}

// Round 2
// 609.773 us; speedup vs baseline: 1.4940x; 1.4940x over previous
//
#include <hip/hip_runtime.h>

// SocialPoolingLayer: fused edge-MLP (relu(pair@W1+b1)@W2+b2, sigmoid gate, elemwise
// product) + scatter-mean by src node.
// Round 2: counting-sort edges by src, then segmented reduction in the MLP kernel.
// R1 showed WRITE_SIZE=825MB (= 51.2M f32 atomics x 16B memory-side RMW) was the
// bottleneck. Sorted edges let each wave flush ~2 partials/col instead of 16 -> 8x
// fewer atomics, plus L2 locality on the src gather.

constexpr int D      = 64;
constexpr int TWO_D  = 128;
constexpr int TILE   = 64;    // edges per block (E=800000 is divisible by 64)
constexpr int BLOCK  = 256;
constexpr int HPAD   = D + 4; // 68 floats: row stride 272B = 16B-aligned, banks spread

// ---------------- sort pre-pass ----------------

__global__ void hist_kernel(const int* __restrict__ ei, int* __restrict__ cnt, int E) {
    const int e = blockIdx.x * blockDim.x + threadIdx.x;
    if (e < E) atomicAdd(&cnt[ei[e]], 1);
}

__global__ void scan_block(const int* __restrict__ cnt, int* __restrict__ off,
                           int* __restrict__ bsum, int N) {
    __shared__ int s[256];
    const int t = threadIdx.x, i = blockIdx.x * 256 + t;
    const int x = (i < N) ? cnt[i] : 0;
    s[t] = x; __syncthreads();
    for (int d = 1; d < 256; d <<= 1) {
        const int v = (t >= d) ? s[t - d] : 0;
        __syncthreads();
        s[t] += v;
        __syncthreads();
    }
    if (i < N) off[i] = s[t] - x;              // exclusive prefix within block
    if (t == 255) bsum[blockIdx.x] = s[255];   // block total
}

__global__ void scan_sums(int* __restrict__ bsum, int nb) {  // nb <= 256
    __shared__ int s[256];
    const int t = threadIdx.x;
    const int x = (t < nb) ? bsum[t] : 0;
    s[t] = x; __syncthreads();
    for (int d = 1; d < 256; d <<= 1) {
        const int v = (t >= d) ? s[t - d] : 0;
        __syncthreads();
        s[t] += v;
        __syncthreads();
    }
    if (t < nb) bsum[t] = s[t] - x;            // exclusive
}

__global__ void add_sums(int* __restrict__ off, const int* __restrict__ bsum, int N) {
    const int i = blockIdx.x * 256 + threadIdx.x;
    if (i < N) off[i] += bsum[blockIdx.x];
}

__global__ void scatter_idx(const int* __restrict__ ei, const int* __restrict__ off,
                            int* __restrict__ cur, int* __restrict__ sorted, int E) {
    const int e = blockIdx.x * blockDim.x + threadIdx.x;
    if (e < E) {
        const int s = ei[e];
        const int p = off[s] + atomicAdd(&cur[s], 1);
        sorted[p] = e;
    }
}

// ---------------- fused MLP + segmented scatter ----------------

__global__ __launch_bounds__(BLOCK, 3)
void edge_mlp_scatter(const float* __restrict__ node_emb,
                      const int*   __restrict__ edge_index,   // [2][E] flat
                      const int*   __restrict__ sorted,       // edge ids sorted by src
                      const float* __restrict__ W1, const float* __restrict__ b1,
                      const float* __restrict__ W2, const float* __restrict__ b2,
                      const float* __restrict__ Wg, const float* __restrict__ bg,
                      float* __restrict__ summed,              // [N][D] pre-zeroed
                      int E)
{
    __shared__ float pairT[TWO_D][TILE];  // [k][e]  32 KB
    __shared__ float hS[TILE][HPAD];      // [e][k]  17 KB (h -> interaction -> gated)
    __shared__ int   srcIds[TILE];

    const int tid = threadIdx.x;

    // ---- stage pair embeddings (gather via sorted edge ids), transposed ----
    {
        const int e  = tid >> 2;        // 0..63
        const int q  = tid & 3;
        const int ide = blockIdx.x * TILE + e;
        if (ide < E) {
            const int eg = sorted[ide];
            const int s  = edge_index[eg];
            const int dn = edge_index[E + eg];
            if (q == 0) srcIds[e] = s;
            const float4* srow = (const float4*)(node_emb + (size_t)s  * D) + q * 4;
            const float4* drow = (const float4*)(node_emb + (size_t)dn * D) + q * 4;
#pragma unroll
            for (int r = 0; r < 4; ++r) {
                const float4 f = srow[r];
                const float4 g = drow[r];
                const int k0 = q * 16 + r * 4;
                pairT[k0 + 0][e] = f.x; pairT[k0 + 1][e] = f.y;
                pairT[k0 + 2][e] = f.z; pairT[k0 + 3][e] = f.w;
                pairT[64 + k0 + 0][e] = g.x; pairT[64 + k0 + 1][e] = g.y;
                pairT[64 + k0 + 2][e] = g.z; pairT[64 + k0 + 3][e] = g.w;
            }
        } else {
            if (q == 0) srcIds[e] = -1;
#pragma unroll
            for (int r = 0; r < 4; ++r) {
                const int k0 = q * 16 + r * 4;
#pragma unroll
                for (int c = 0; c < 4; ++c) { pairT[k0 + c][e] = 0.f; pairT[64 + k0 + c][e] = 0.f; }
            }
        }
    }
    __syncthreads();

    const int ty = tid >> 4;      // 0..15 -> rows 4ty..4ty+3 (wave w owns rows 16w..16w+15)
    const int tx = tid & 15;      // 0..15 -> cols 4tx..4tx+3
    const int r0 = 4 * ty, c0 = 4 * tx;

    // ---- GEMM1: h = relu(pair @ W1 + b1) ----
    float acc[4][4] = {};
#pragma unroll 4
    for (int k = 0; k < TWO_D; ++k) {
        const float4 a = *(const float4*)&pairT[k][r0];
        const float4 b = *(const float4*)&W1[k * D + c0];
        const float av[4] = {a.x, a.y, a.z, a.w};
        const float bv[4] = {b.x, b.y, b.z, b.w};
#pragma unroll
        for (int i = 0; i < 4; ++i)
#pragma unroll
            for (int j = 0; j < 4; ++j) acc[i][j] += av[i] * bv[j];
    }
    {
        const float4 bb = *(const float4*)&b1[c0];
        const float bv[4] = {bb.x, bb.y, bb.z, bb.w};
#pragma unroll
        for (int i = 0; i < 4; ++i) {
            float4 h;
            h.x = fmaxf(acc[i][0] + bv[0], 0.f);
            h.y = fmaxf(acc[i][1] + bv[1], 0.f);
            h.z = fmaxf(acc[i][2] + bv[2], 0.f);
            h.w = fmaxf(acc[i][3] + bv[3], 0.f);
            *(float4*)&hS[r0 + i][c0] = h;
        }
    }
    __syncthreads();

    // ---- GEMM2: interaction = h @ W2 + b2 ----
    float acc2[4][4] = {};
#pragma unroll 2
    for (int k4 = 0; k4 < D; k4 += 4) {
        float4 ar[4];
#pragma unroll
        for (int i = 0; i < 4; ++i) ar[i] = *(const float4*)&hS[r0 + i][k4];
#pragma unroll
        for (int kk = 0; kk < 4; ++kk) {
            const float4 b = *(const float4*)&W2[(k4 + kk) * D + c0];
            const float bv[4] = {b.x, b.y, b.z, b.w};
#pragma unroll
            for (int i = 0; i < 4; ++i) {
                const float a = (&ar[i].x)[kk];
#pragma unroll
                for (int j = 0; j < 4; ++j) acc2[i][j] += a * bv[j];
            }
        }
    }
    {
        const float4 bb = *(const float4*)&b2[c0];
#pragma unroll
        for (int i = 0; i < 4; ++i) {
            acc2[i][0] += bb.x; acc2[i][1] += bb.y; acc2[i][2] += bb.z; acc2[i][3] += bb.w;
        }
    }
    __syncthreads();
#pragma unroll
    for (int i = 0; i < 4; ++i) {
        float4 v;
        v.x = acc2[i][0]; v.y = acc2[i][1]; v.z = acc2[i][2]; v.w = acc2[i][3];
        *(float4*)&hS[r0 + i][c0] = v;
    }
    __syncthreads();

    // ---- GEMM3: gate_pre = interaction @ Wg + bg ----
    float accg[4][4] = {};
#pragma unroll 2
    for (int k4 = 0; k4 < D; k4 += 4) {
        float4 ar[4];
#pragma unroll
        for (int i = 0; i < 4; ++i) ar[i] = *(const float4*)&hS[r0 + i][k4];
#pragma unroll
        for (int kk = 0; kk < 4; ++kk) {
            const float4 b = *(const float4*)&Wg[(k4 + kk) * D + c0];
            const float bv[4] = {b.x, b.y, b.z, b.w};
#pragma unroll
            for (int i = 0; i < 4; ++i) {
                const float a = (&ar[i].x)[kk];
#pragma unroll
                for (int j = 0; j < 4; ++j) accg[i][j] += a * bv[j];
            }
        }
    }
    __syncthreads();   // GEMM3 reads of hS done before overwriting with gated values

    // ---- gated = interaction * sigmoid(gate_pre), into hS ----
    {
        const float4 bb = *(const float4*)&bg[c0];
        const float bgv[4] = {bb.x, bb.y, bb.z, bb.w};
#pragma unroll
        for (int i = 0; i < 4; ++i) {
            float4 v;
#pragma unroll
            for (int j = 0; j < 4; ++j) {
                const float g = 1.0f / (1.0f + __expf(-(accg[i][j] + bgv[j])));
                (&v.x)[j] = acc2[i][j] * g;
            }
            *(float4*)&hS[r0 + i][c0] = v;
        }
    }
    __syncthreads();

    // ---- per-wave segmented reduction over 16 sorted rows, flush per segment ----
    {
        const int wv    = tid >> 6;      // wave 0..3 owns rows 16wv..16wv+15
        const int lane  = tid & 63;      // column
        const int rbase = wv * 16;
        float vals[16];
#pragma unroll
        for (int i = 0; i < 16; ++i) vals[i] = hS[rbase + i][lane];

        float run = 0.f;
        int   prev = srcIds[rbase];
#pragma unroll
        for (int i = 0; i < 16; ++i) {
            const int s = srcIds[rbase + i];    // wave-uniform -> no divergence
            if (s != prev) {
                if (prev >= 0) unsafeAtomicAdd(&summed[(size_t)prev * D + lane], run);
                run = 0.f;
                prev = s;
            }
            run += vals[i];
        }
        if (prev >= 0) unsafeAtomicAdd(&summed[(size_t)prev * D + lane], run);
    }
}

__global__ void finalize_mean(float* __restrict__ out,
                              const int* __restrict__ cnt,
                              int total)
{
    const int i = blockIdx.x * blockDim.x + threadIdx.x;
    if (i < total) {
        out[i] = out[i] / fmaxf((float)cnt[i >> 6], 1.0f);
    }
}

extern "C" void kernel_launch(void* const* d_in, const int* in_sizes, int n_in,
                              void* d_out, int out_size, void* d_ws, size_t ws_size,
                              hipStream_t stream) {
    const float* node_emb   = (const float*)d_in[0];
    const int*   edge_index = (const int*)d_in[1];
    const float* W1 = (const float*)d_in[2];
    const float* b1 = (const float*)d_in[3];
    const float* W2 = (const float*)d_in[4];
    const float* b2 = (const float*)d_in[5];
    const float* Wg = (const float*)d_in[6];
    const float* bg = (const float*)d_in[7];

    const int N = in_sizes[0] / D;
    const int E = in_sizes[1] / 2;

    // workspace layout (ints): cnt[N] | off[N] | cur[N] | bsum[4096] | sorted[E]
    int* cnt    = (int*)d_ws;
    int* off    = cnt + N;
    int* cur    = off + N;
    int* bsum   = cur + N;
    int* sorted = bsum + 4096;

    float* summed = (float*)d_out;

    hipMemsetAsync(cnt, 0, sizeof(int) * (size_t)N, stream);
    hipMemsetAsync(cur, 0, sizeof(int) * (size_t)N, stream);
    hipMemsetAsync(summed, 0, sizeof(float) * (size_t)N * D, stream);

    const int eblocks = (E + 255) / 256;
    const int nblocks = (N + 255) / 256;   // 196 for N=50000 (must be <= 256)

    hist_kernel <<<eblocks, 256, 0, stream>>>(edge_index, cnt, E);
    scan_block  <<<nblocks, 256, 0, stream>>>(cnt, off, bsum, N);
    scan_sums   <<<1,       256, 0, stream>>>(bsum, nblocks);
    add_sums    <<<nblocks, 256, 0, stream>>>(off, bsum, N);
    scatter_idx <<<eblocks, 256, 0, stream>>>(edge_index, off, cur, sorted, E);

    const int ntiles = (E + TILE - 1) / TILE;
    edge_mlp_scatter<<<ntiles, BLOCK, 0, stream>>>(node_emb, edge_index, sorted,
                                                   W1, b1, W2, b2, Wg, bg,
                                                   summed, E);

    const int total = N * D;
    finalize_mean<<<(total + 255) / 256, 256, 0, stream>>>(summed, cnt, total);
}

// Round 3
// 310.930 us; speedup vs baseline: 2.9300x; 1.9611x over previous
//
#include <hip/hip_runtime.h>

// SocialPoolingLayer: fused edge-MLP (relu(pair@W1+b1)@W2+b2, sigmoid gate, elemwise
// product) + scatter-mean by src node.
// Round 3: bf16 MFMA (16x16x32) for all three GEMMs. R2 was VALU-bound (52% VALUBusy,
// 4096 fp32 FMA insts/wave). One wave now owns 16 sorted edges end-to-end:
// gather->bf16->LDS (A-layout), MFMA vs pre-packed B-fragments (global, L1-resident),
// gate, segmented-reduction flush. Sort pre-pass unchanged from R2.

typedef unsigned short ushort_t;
typedef __attribute__((ext_vector_type(8))) short     bf16x8;   // 8 bf16 = 4 VGPRs
typedef __attribute__((ext_vector_type(8))) unsigned short u16x8;
typedef __attribute__((ext_vector_type(4))) float     f32x4;

constexpr int D        = 64;
constexpr int TILE     = 64;     // edges per block (4 waves x 16 edges)
constexpr int BLOCK    = 256;
constexpr int PAIR_STR = 136;    // pair row stride in bf16 (128 + 8 pad), 272B, 16B-aligned
constexpr int H_STR    = 72;     // h/interaction row stride in bf16 (64 + 8 pad), 144B
constexpr int G_STR    = 68;     // gated row stride in f32 (64 + 4 pad)
constexpr int NFRAG    = 32;     // 16 (W1) + 8 (W2) + 8 (Wg) B-fragments

static __device__ __forceinline__ ushort_t f2bf(float f) {
    union { float f; unsigned int u; } v; v.f = f;
    const unsigned int r = v.u + 0x7FFFu + ((v.u >> 16) & 1u);   // RNE
    return (ushort_t)(r >> 16);
}

// ---------------- sort pre-pass (unchanged from R2) ----------------

__global__ void hist_kernel(const int* __restrict__ ei, int* __restrict__ cnt, int E) {
    const int e = blockIdx.x * blockDim.x + threadIdx.x;
    if (e < E) atomicAdd(&cnt[ei[e]], 1);
}

__global__ void scan_block(const int* __restrict__ cnt, int* __restrict__ off,
                           int* __restrict__ bsum, int N) {
    __shared__ int s[256];
    const int t = threadIdx.x, i = blockIdx.x * 256 + t;
    const int x = (i < N) ? cnt[i] : 0;
    s[t] = x; __syncthreads();
    for (int d = 1; d < 256; d <<= 1) {
        const int v = (t >= d) ? s[t - d] : 0;
        __syncthreads();
        s[t] += v;
        __syncthreads();
    }
    if (i < N) off[i] = s[t] - x;
    if (t == 255) bsum[blockIdx.x] = s[255];
}

__global__ void scan_sums(int* __restrict__ bsum, int nb) {  // nb <= 256
    __shared__ int s[256];
    const int t = threadIdx.x;
    const int x = (t < nb) ? bsum[t] : 0;
    s[t] = x; __syncthreads();
    for (int d = 1; d < 256; d <<= 1) {
        const int v = (t >= d) ? s[t - d] : 0;
        __syncthreads();
        s[t] += v;
        __syncthreads();
    }
    if (t < nb) bsum[t] = s[t] - x;
}

__global__ void add_sums(int* __restrict__ off, const int* __restrict__ bsum, int N) {
    const int i = blockIdx.x * 256 + threadIdx.x;
    if (i < N) off[i] += bsum[blockIdx.x];
}

__global__ void scatter_idx(const int* __restrict__ ei, const int* __restrict__ off,
                            int* __restrict__ cur, int* __restrict__ sorted, int E) {
    const int e = blockIdx.x * blockDim.x + threadIdx.x;
    if (e < E) {
        const int s = ei[e];
        const int p = off[s] + atomicAdd(&cur[s], 1);
        sorted[p] = e;
    }
}

// ---------------- weight packing: B-operand fragment order, bf16 ----------------
// frag f, lane l, elem j  ->  W[k][n],  k = kc*32 + (l>>4)*8 + j,  n = nt*16 + (l&15)
// f in [0,16): W1 (nt=f>>2, kc=f&3); [16,24): W2 (nt=(f-16)>>1, kc=(f-16)&1); [24,32): Wg.

__global__ void pack_weights(const float* __restrict__ W1, const float* __restrict__ W2,
                             const float* __restrict__ Wg, ushort_t* __restrict__ wpack) {
    const int t = blockIdx.x * 256 + threadIdx.x;
    if (t >= NFRAG * 512) return;
    const int f = t >> 9;
    const int l = (t >> 3) & 63;
    const int j = t & 7;
    const float* W; int nt, kc;
    if (f < 16)      { W = W1; nt = f >> 2;        kc = f & 3; }
    else if (f < 24) { W = W2; nt = (f - 16) >> 1; kc = (f - 16) & 1; }
    else             { W = Wg; nt = (f - 24) >> 1; kc = (f - 24) & 1; }
    const int k = kc * 32 + (l >> 4) * 8 + j;
    const int n = nt * 16 + (l & 15);
    wpack[t] = f2bf(W[k * 64 + n]);
}

// ---------------- fused MFMA MLP + segmented scatter ----------------

__global__ __launch_bounds__(BLOCK, 3)
void edge_mlp_mfma(const float* __restrict__ node_emb,
                   const int*   __restrict__ edge_index,   // [2][E] flat
                   const int*   __restrict__ sorted,       // edge ids sorted by src
                   const ushort_t* __restrict__ wpack,     // 32 packed B-frags
                   const float* __restrict__ b1, const float* __restrict__ b2,
                   const float* __restrict__ bg,
                   float* __restrict__ summed,             // [N][D] pre-zeroed
                   int E)
{
    __shared__ ushort_t pairA[TILE][PAIR_STR];  // 17408 B  [edge][k] bf16
    __shared__ ushort_t hA[TILE][H_STR];        //  9216 B  h, then interaction (bf16)
    __shared__ float    gatedS[TILE][G_STR];    // 17408 B
    __shared__ int      srcIds[TILE];

    const int tid = threadIdx.x;

    // ---- stage: gather fp32 rows, convert bf16, store A-layout (wave-local rows) ----
    {
        const int e = tid >> 2, q = tid & 3;        // e: edge slot, q: 16-float quarter
        const int ide = blockIdx.x * TILE + e;
        if (ide < E) {
            const int eg = sorted[ide];
            const int s  = edge_index[eg];
            const int dn = edge_index[E + eg];
            if (q == 0) srcIds[e] = s;
            const float4* sr = (const float4*)(node_emb + (size_t)s  * D + q * 16);
            const float4* dr = (const float4*)(node_emb + (size_t)dn * D + q * 16);
            const float4 s0 = sr[0], s1 = sr[1], s2 = sr[2], s3 = sr[3];
            const float4 d0 = dr[0], d1 = dr[1], d2 = dr[2], d3 = dr[3];
            u16x8 p;
            p[0]=f2bf(s0.x); p[1]=f2bf(s0.y); p[2]=f2bf(s0.z); p[3]=f2bf(s0.w);
            p[4]=f2bf(s1.x); p[5]=f2bf(s1.y); p[6]=f2bf(s1.z); p[7]=f2bf(s1.w);
            *(u16x8*)&pairA[e][q * 16] = p;
            p[0]=f2bf(s2.x); p[1]=f2bf(s2.y); p[2]=f2bf(s2.z); p[3]=f2bf(s2.w);
            p[4]=f2bf(s3.x); p[5]=f2bf(s3.y); p[6]=f2bf(s3.z); p[7]=f2bf(s3.w);
            *(u16x8*)&pairA[e][q * 16 + 8] = p;
            p[0]=f2bf(d0.x); p[1]=f2bf(d0.y); p[2]=f2bf(d0.z); p[3]=f2bf(d0.w);
            p[4]=f2bf(d1.x); p[5]=f2bf(d1.y); p[6]=f2bf(d1.z); p[7]=f2bf(d1.w);
            *(u16x8*)&pairA[e][64 + q * 16] = p;
            p[0]=f2bf(d2.x); p[1]=f2bf(d2.y); p[2]=f2bf(d2.z); p[3]=f2bf(d2.w);
            p[4]=f2bf(d3.x); p[5]=f2bf(d3.y); p[6]=f2bf(d3.z); p[7]=f2bf(d3.w);
            *(u16x8*)&pairA[e][64 + q * 16 + 8] = p;
        } else {
            if (q == 0) srcIds[e] = -1;
            const u16x8 z = {0,0,0,0,0,0,0,0};
            *(u16x8*)&pairA[e][q * 16]          = z;
            *(u16x8*)&pairA[e][q * 16 + 8]      = z;
            *(u16x8*)&pairA[e][64 + q * 16]     = z;
            *(u16x8*)&pairA[e][64 + q * 16 + 8] = z;
        }
    }
    __syncthreads();

    const int w    = tid >> 6;        // wave id: owns edge rows 16w..16w+15
    const int ln   = tid & 63;
    const int quad = ln >> 4;
    const int cn   = ln & 15;         // output column within an N-tile / A-operand row
    const int mrow = 16 * w + cn;     // A-operand row this lane reads
    const int orow = 16 * w + quad * 4;  // C/D rows this lane holds (orow..orow+3)

    // ---- GEMM1: h = relu(pair @ W1 + b1), M=16 K=128 N=64 ----
    bf16x8 a1f[4];
#pragma unroll
    for (int kc = 0; kc < 4; ++kc)
        a1f[kc] = *(const bf16x8*)&pairA[mrow][kc * 32 + quad * 8];

    f32x4 acc1[4];
#pragma unroll
    for (int nt = 0; nt < 4; ++nt) {
        const float b = b1[nt * 16 + cn];
        acc1[nt] = (f32x4){b, b, b, b};
    }
#pragma unroll
    for (int nt = 0; nt < 4; ++nt)
#pragma unroll
        for (int kc = 0; kc < 4; ++kc) {
            const bf16x8 bf = *(const bf16x8*)(wpack + ((nt * 4 + kc) * 64 + ln) * 8);
            acc1[nt] = __builtin_amdgcn_mfma_f32_16x16x32_bf16(a1f[kc], bf, acc1[nt], 0, 0, 0);
        }
#pragma unroll
    for (int nt = 0; nt < 4; ++nt)
#pragma unroll
        for (int r = 0; r < 4; ++r)
            hA[orow + r][nt * 16 + cn] = f2bf(fmaxf(acc1[nt][r], 0.f));
    __syncthreads();

    // ---- GEMM2: interaction = h @ W2 + b2, K=64 ----
    bf16x8 a2f[2];
#pragma unroll
    for (int kc = 0; kc < 2; ++kc)
        a2f[kc] = *(const bf16x8*)&hA[mrow][kc * 32 + quad * 8];

    f32x4 acc2[4];
#pragma unroll
    for (int nt = 0; nt < 4; ++nt) {
        const float b = b2[nt * 16 + cn];
        acc2[nt] = (f32x4){b, b, b, b};
    }
#pragma unroll
    for (int nt = 0; nt < 4; ++nt)
#pragma unroll
        for (int kc = 0; kc < 2; ++kc) {
            const bf16x8 bf = *(const bf16x8*)(wpack + ((16 + nt * 2 + kc) * 64 + ln) * 8);
            acc2[nt] = __builtin_amdgcn_mfma_f32_16x16x32_bf16(a2f[kc], bf, acc2[nt], 0, 0, 0);
        }
    __syncthreads();   // all a2f loads done before hA overwrite
#pragma unroll
    for (int nt = 0; nt < 4; ++nt)
#pragma unroll
        for (int r = 0; r < 4; ++r)
            hA[orow + r][nt * 16 + cn] = f2bf(acc2[nt][r]);
    __syncthreads();

    // ---- GEMM3: gate_pre = interaction @ Wg + bg, K=64 ----
    bf16x8 a3f[2];
#pragma unroll
    for (int kc = 0; kc < 2; ++kc)
        a3f[kc] = *(const bf16x8*)&hA[mrow][kc * 32 + quad * 8];

    f32x4 accg[4];
#pragma unroll
    for (int nt = 0; nt < 4; ++nt) {
        const float b = bg[nt * 16 + cn];
        accg[nt] = (f32x4){b, b, b, b};
    }
#pragma unroll
    for (int nt = 0; nt < 4; ++nt)
#pragma unroll
        for (int kc = 0; kc < 2; ++kc) {
            const bf16x8 bf = *(const bf16x8*)(wpack + ((24 + nt * 2 + kc) * 64 + ln) * 8);
            accg[nt] = __builtin_amdgcn_mfma_f32_16x16x32_bf16(a3f[kc], bf, accg[nt], 0, 0, 0);
        }

    // ---- gated = interaction * sigmoid(gate_pre) -> LDS (C-layout matches) ----
#pragma unroll
    for (int nt = 0; nt < 4; ++nt)
#pragma unroll
        for (int r = 0; r < 4; ++r) {
            const float g = 1.0f / (1.0f + __expf(-accg[nt][r]));
            gatedS[orow + r][nt * 16 + cn] = acc2[nt][r] * g;
        }
    __syncthreads();

    // ---- per-wave segmented reduction over its 16 sorted rows ----
    {
        const int rbase = 16 * w;
        float run = 0.f;
        int   prev = srcIds[rbase];
#pragma unroll
        for (int i = 0; i < 16; ++i) {
            const int s = srcIds[rbase + i];      // wave-uniform
            const float v = gatedS[rbase + i][ln];
            if (s != prev) {
                if (prev >= 0) unsafeAtomicAdd(&summed[(size_t)prev * D + ln], run);
                run = 0.f;
                prev = s;
            }
            run += v;
        }
        if (prev >= 0) unsafeAtomicAdd(&summed[(size_t)prev * D + ln], run);
    }
}

__global__ void finalize_mean(float* __restrict__ out,
                              const int* __restrict__ cnt,
                              int total)
{
    const int i = blockIdx.x * blockDim.x + threadIdx.x;
    if (i < total) {
        out[i] = out[i] / fmaxf((float)cnt[i >> 6], 1.0f);
    }
}

extern "C" void kernel_launch(void* const* d_in, const int* in_sizes, int n_in,
                              void* d_out, int out_size, void* d_ws, size_t ws_size,
                              hipStream_t stream) {
    const float* node_emb   = (const float*)d_in[0];
    const int*   edge_index = (const int*)d_in[1];
    const float* W1 = (const float*)d_in[2];
    const float* b1 = (const float*)d_in[3];
    const float* W2 = (const float*)d_in[4];
    const float* b2 = (const float*)d_in[5];
    const float* Wg = (const float*)d_in[6];
    const float* bg = (const float*)d_in[7];

    const int N = in_sizes[0] / D;
    const int E = in_sizes[1] / 2;

    // ws layout (ints): cnt[N] | off[N] | cur[N] | bsum[4096] | sorted[E] | wpack (bf16)
    int* cnt    = (int*)d_ws;
    int* off    = cnt + N;
    int* cur    = off + N;
    int* bsum   = cur + N;
    int* sorted = bsum + 4096;
    ushort_t* wpack = (ushort_t*)(sorted + E);   // 32*512 bf16 = 32 KB, 16B-aligned

    float* summed = (float*)d_out;

    hipMemsetAsync(cnt, 0, sizeof(int) * (size_t)N, stream);
    hipMemsetAsync(cur, 0, sizeof(int) * (size_t)N, stream);
    hipMemsetAsync(summed, 0, sizeof(float) * (size_t)N * D, stream);

    const int eblocks = (E + 255) / 256;
    const int nblocks = (N + 255) / 256;   // 196 for N=50000 (<= 256)

    hist_kernel  <<<eblocks, 256, 0, stream>>>(edge_index, cnt, E);
    scan_block   <<<nblocks, 256, 0, stream>>>(cnt, off, bsum, N);
    scan_sums    <<<1,       256, 0, stream>>>(bsum, nblocks);
    add_sums     <<<nblocks, 256, 0, stream>>>(off, bsum, N);
    scatter_idx  <<<eblocks, 256, 0, stream>>>(edge_index, off, cur, sorted, E);
    pack_weights <<<(NFRAG * 512 + 255) / 256, 256, 0, stream>>>(W1, W2, Wg, wpack);

    const int ntiles = (E + TILE - 1) / TILE;
    edge_mlp_mfma<<<ntiles, BLOCK, 0, stream>>>(node_emb, edge_index, sorted, wpack,
                                                b1, b2, bg, summed, E);

    const int total = N * D;
    finalize_mean<<<(total + 255) / 256, 256, 0, stream>>>(summed, cnt, total);
}